// Round 4
// baseline (163.004 us; speedup 1.0000x reference)
//
#include <hip/hip_runtime.h>
#include <math.h>

#define B_N 2048
#define DIM 32
#define K_N 10
#define NP  528          // sorted pairs (i<=j)
#define NCOLP 640        // padded column count (5 tiles x 128)
#define CH 32            // samples per chunk
#define TILE 128
#define NT 5
#define NBLK (NT*NT*K_N)

// ---- ws layout (4-byte words) ----
#define WS_LOSS   0
#define WS_CTR    1
#define WS_CW     2
#define WS_CURSOR 12
#define WS_OFFS   22
#define WS_KB     32
#define WS_DIFFC  2080                 // 16B aligned; 2048*32 floats
#define WS_V      67616                // 16B aligned; (2048+32)*640 floats
#define WS_V_ROWS (B_N + CH)
#define WS_NEED_BYTES ((size_t)(WS_V + (size_t)WS_V_ROWS * NCOLP) * 4)

__device__ __forceinline__ float c2f(float x) {
  float r = sqrtf(fabsf(x) + 0.25f) - 0.5f;
  return (x >= 0.f) ? r : -r;
}
__device__ __forceinline__ float c3f(float x) {
  float r = cbrtf(fabsf(x) + 0.19245008973f) - 0.57735026919f;
  return (x >= 0.f) ? r : -r;
}
__device__ __forceinline__ float c4f(float x) {
  float r = sqrtf(sqrtf(fabsf(x) + 0.15749013123f)) - 0.62996052494f;
  return (x >= 0.f) ? r : -r;
}
#define T4C1 (sqrtf(sqrtf(1.f + 0.15749013123f)) - 0.62996052494f)

// col -> (u,v) with d[32]=1 (ones), d[33]=0 (pad)
__device__ __forceinline__ void decode_col(int g, int& u, int& v) {
  if (g < NP) {
    int j = 0;
    while ((j + 1) * (j + 2) / 2 <= g) ++j;
    u = g - j * (j + 1) / 2; v = j;
  } else if (g < 560) { u = g - NP; v = 32; }
  else if (g == 560)  { u = 32; v = 32; }
  else                { u = 33; v = 33; }
}

// helper (MODE 1: src == diffc)
__device__ __forceinline__ const float* diffcRow(const float* src, int row) {
  return src + (size_t)row * DIM;
}

// ---- kernel 1: argmax assignment + counts ----
__global__ void k_assign(const float* __restrict__ logits, int* __restrict__ cw,
                         int* __restrict__ kb) {
  int b = blockIdx.x * 256 + threadIdx.x;
  if (b >= B_N) return;
  const float* lg = logits + (size_t)b * K_N;
  float best = lg[0]; int bi = 0;
  #pragma unroll
  for (int k = 1; k < K_N; ++k) { float v = lg[k]; if (v > best) { best = v; bi = k; } }
  kb[b] = bi;
  atomicAdd(&cw[bi], 1);
}

// ---- kernel 2: exclusive scan over K=10 ----
__global__ void k_scan(const int* __restrict__ cw, int* __restrict__ offs) {
  if (threadIdx.x == 0) { int s = 0; for (int k = 0; k < K_N; ++k) { offs[k] = s; s += cw[k]; } }
}

// ---- kernel 3: compact scatter of diff vectors ----
__global__ void k_scatter(const float* __restrict__ emb, const float* __restrict__ cen,
                          const int* __restrict__ kb, const int* __restrict__ offs,
                          int* __restrict__ cursor, float* __restrict__ diffc) {
  int b = blockIdx.x * 256 + threadIdx.x;
  if (b >= B_N) return;
  int k = kb[b];
  int pos = offs[k] + atomicAdd(&cursor[k], 1);
  const float4* e4 = reinterpret_cast<const float4*>(emb + (size_t)b * DIM);
  const float4* c4p = reinterpret_cast<const float4*>(cen + (size_t)k * DIM);
  float4* o4 = reinterpret_cast<float4*>(diffc + (size_t)pos * DIM);
  #pragma unroll
  for (int q = 0; q < 8; ++q) {
    float4 e = e4[q], c = c4p[q];
    o4[q] = make_float4(e.x - c.x, e.y - c.y, e.z - c.z, e.w - c.w);
  }
}

// ---- kernel 4: expand diffc -> V[2048+pad][640] (column matrix) ----
__global__ __launch_bounds__(256) void k_expand(const float* __restrict__ diffc,
                                                float* __restrict__ V) {
  __shared__ float sd[32][36];
  __shared__ unsigned char tu[NCOLP], tv[NCOLP];
  const int t = threadIdx.x;
  const int base = blockIdx.x * 32;
  for (int c = t; c < NCOLP; c += 256) {
    int u, v; decode_col(c, u, v);
    tu[c] = (unsigned char)u; tv[c] = (unsigned char)v;
  }
  {
    int row = t >> 3, d4 = t & 7;
    float4 v = *reinterpret_cast<const float4*>(&diffc[(size_t)(base + row) * DIM + d4 * 4]);
    *reinterpret_cast<float4*>(&sd[row][d4 * 4]) = v;
    if (d4 == 0) { sd[row][32] = 1.f; sd[row][33] = 0.f; }
  }
  __syncthreads();
  for (int s = 0; s < 32; ++s) {
    float* vr = V + (size_t)(base + s) * NCOLP;
    #pragma unroll
    for (int p = 0; p < 3; ++p) {
      int c = t + p * 256;
      if (c < NCOLP) vr[c] = sd[s][tu[c]] * sd[s][tv[c]];
    }
  }
}

// ---- kernel 4b: zero the pad rows of V (rows B_N .. B_N+CH-1) ----
__global__ void k_padzero(float* __restrict__ V) {
  int idx = blockIdx.x * 256 + threadIdx.x;
  if (idx < CH * NCOLP) V[(size_t)B_N * NCOLP + idx] = 0.f;
}

// ---- kernel 5: Gram + fused loss. MODE 0: V precomputed; MODE 1: products in-kernel ----
template<int MODE>
__global__ __launch_bounds__(256) void k_main(const float* __restrict__ src,
                                              const int* __restrict__ cw,
                                              const int* __restrict__ offs,
                                              float* __restrict__ lossAcc,
                                              int* __restrict__ ctr,
                                              float* __restrict__ out) {
  const int k  = blockIdx.z;
  const int Pt = blockIdx.y, Qt = blockIdx.x;
  const int nb = cw[k], boff = offs[k];
  const int t  = threadIdx.x;

  __shared__ __align__(16) float sPa[MODE ? CH : 1][64], sPb[MODE ? CH : 1][64];
  __shared__ __align__(16) float sQa[CH][64], sQb[CH][64];
  __shared__ __align__(16) float sd[MODE ? CH : 1][36];
  __shared__ unsigned char tIP[2][TILE], tIQ[2][TILE];
  __shared__ float sred[4];

  // decode column identity tables (also per-thread u,v for MODE 1 products)
  int myu, myv;
  {
    int side = t >> 7, c = t & 127;
    int g = (side ? Qt : Pt) * TILE + c;
    decode_col(g, myu, myv);
    if (side) { tIQ[0][c] = (unsigned char)myu; tIQ[1][c] = (unsigned char)myv; }
    else      { tIP[0][c] = (unsigned char)myu; tIP[1][c] = (unsigned char)myv; }
  }
  __syncthreads();

  float acc[8][8];
  #pragma unroll
  for (int a = 0; a < 8; ++a)
    #pragma unroll
    for (int c = 0; c < 8; ++c) acc[a][c] = 0.f;

  const int tp = t >> 4, tq = t & 15;
  const float* Vp = nullptr;
  if (MODE == 0) Vp = src + (size_t)boff * NCOLP + Pt * TILE + tp * 8;

  for (int c0 = 0; c0 < nb; c0 += CH) {
    if (MODE == 0) {
      // stage Q panel [CH rows][128 cols]; pad rows of V are zero so no predicate
      // needed beyond the global pad region (V has CH extra zero rows).
      #pragma unroll
      for (int pass = 0; pass < 4; ++pass) {
        int row = pass * 8 + (t >> 5), c4 = t & 31;
        float4 v = *reinterpret_cast<const float4*>(
              &src[(size_t)(boff + c0 + row) * NCOLP + Qt * TILE + c4 * 4]);
        float* dst = (c4 & 1) ? &sQb[row][(c4 >> 1) * 4] : &sQa[row][(c4 >> 1) * 4];
        *reinterpret_cast<float4*>(dst) = v;
      }
    } else {
      // stage raw d
      {
        int row = t >> 3, d4 = t & 7;
        float4 v = make_float4(0.f, 0.f, 0.f, 0.f);
        if (c0 + row < nb)
          v = *reinterpret_cast<const float4*>(&diffcRow(src, boff + c0 + row)[d4 * 4]);
        *reinterpret_cast<float4*>(&sd[row][d4 * 4]) = v;
        if (d4 == 0) { sd[row][32] = (c0 + row < nb) ? 1.f : 0.f; sd[row][33] = 0.f; }
      }
      __syncthreads();
      // products into split arrays
      {
        int side = t >> 7, c = t & 127;
        float* dst = (side ? ((c & 4) ? &sQb[0][0] : &sQa[0][0])
                           : ((c & 4) ? &sPb[0][0] : &sPa[0][0]))
                     + ((c >> 3) * 4 + (c & 3));
        #pragma unroll
        for (int bb = 0; bb < CH; ++bb)
          dst[bb * 64] = sd[bb][myu] * sd[bb][myv];
      }
    }
    __syncthreads();

    const float* pc = (MODE == 0) ? (Vp + (size_t)c0 * NCOLP) : nullptr;
    #pragma unroll
    for (int bb = 0; bb < CH; ++bb) {
      float4 q0 = *reinterpret_cast<const float4*>(&sQa[bb][tq * 4]);
      float4 q1 = *reinterpret_cast<const float4*>(&sQb[bb][tq * 4]);
      float4 p0, p1;
      if (MODE == 0) {
        const float* pr = pc + (size_t)bb * NCOLP;
        p0 = *reinterpret_cast<const float4*>(pr);
        p1 = *reinterpret_cast<const float4*>(pr + 4);
      } else {
        p0 = *reinterpret_cast<const float4*>(&sPa[bb][tp * 4]);
        p1 = *reinterpret_cast<const float4*>(&sPb[bb][tp * 4]);
      }
      float pa[8] = {p0.x, p0.y, p0.z, p0.w, p1.x, p1.y, p1.z, p1.w};
      float qa[8] = {q0.x, q0.y, q0.z, q0.w, q1.x, q1.y, q1.z, q1.w};
      #pragma unroll
      for (int a = 0; a < 8; ++a)
        #pragma unroll
        for (int c = 0; c < 8; ++c)
          acc[a][c] += pa[a] * qa[c];
    }
    __syncthreads();
  }

  // ---- fused epilogue (validated in round 2) ----
  const float inv_cnt = 1.f / ((float)nb + 1e-7f);
  float sum = 0.f;
  #pragma unroll
  for (int a = 0; a < 8; ++a) {
    int P = Pt * TILE + tp * 8 + a;
    int i = tIP[0][tp * 8 + a], j = tIP[1][tp * 8 + a];
    #pragma unroll
    for (int c = 0; c < 8; ++c) {
      int Q = Qt * TILE + tq * 8 + c;
      int l = tIQ[0][tq * 8 + c], m = tIQ[1][tq * 8 + c];
      float g = acc[a][c];
      if (P < NP) {
        if (Q < NP) {
          int s0 = min(i, l), a1 = max(i, l), a2 = min(j, m), s3 = max(j, m);
          int s1 = min(a1, a2), s2 = max(a1, a2);
          bool e01 = (s0 == s1), e12 = (s1 == s2), e23 = (s2 == s3);
          float wgt, tgt = 0.f;
          if (e01 && e12 && e23)                 wgt = 0.f;
          else if (e01 && e23)                   { wgt = 2.f / 9.f; tgt = T4C1; }
          else if ((e01 && e12) || (e12 && e23)) wgt = 0.25f;
          else if (e01 || e12 || e23)            wgt = 5.f / 24.f;
          else                                   wgt = 1.f / 6.f;
          float d = c4f(g) - tgt;
          sum += 0.125f * wgt * d * d;
        } else if (Q < 560) {
          int ll = Q - NP;
          if (ll >= j) { float d = c3f(g); sum += 0.25f * d * d; }
        } else if (Q == 560) {
          if (i < j) { float d = c2f(g * inv_cnt); sum += 0.5f * d * d; }
        }
      } else if (P < 560 && Q == 560) {
        float m1 = g * inv_cnt;
        sum += m1 * m1;
      }
    }
  }

  #pragma unroll
  for (int off = 32; off > 0; off >>= 1) sum += __shfl_down(sum, off, 64);
  if ((t & 63) == 0) sred[t >> 6] = sum;
  __syncthreads();
  if (t == 0) {
    float s = sred[0] + sred[1] + sred[2] + sred[3];
    atomicAdd(lossAcc, s * ((float)nb * (1.f / (float)B_N)));
    __threadfence();
    if (atomicAdd(ctr, 1) == NBLK - 1) out[0] = atomicAdd(lossAcc, 0.f);
  }
}

extern "C" void kernel_launch(void* const* d_in, const int* in_sizes, int n_in,
                              void* d_out, int out_size, void* d_ws, size_t ws_size,
                              hipStream_t stream) {
  const float* emb = (const float*)d_in[0];
  const float* cen = (const float*)d_in[1];
  const float* lg  = (const float*)d_in[2];
  float* out = (float*)d_out;

  int*   wsi    = (int*)d_ws;
  float* wsf    = (float*)d_ws;
  float* lossA  = wsf + WS_LOSS;
  int*   ctr    = wsi + WS_CTR;
  int*   cw     = wsi + WS_CW;
  int*   cursor = wsi + WS_CURSOR;
  int*   offsp  = wsi + WS_OFFS;
  int*   kb     = wsi + WS_KB;
  float* diffc  = wsf + WS_DIFFC;
  float* V      = wsf + WS_V;

  (void)hipMemsetAsync(d_ws, 0, 64 * 4, stream);
  k_assign <<<B_N / 256, 256, 0, stream>>>(lg, cw, kb);
  k_scan   <<<1, 64, 0, stream>>>(cw, offsp);
  k_scatter<<<B_N / 256, 256, 0, stream>>>(emb, cen, kb, offsp, cursor, diffc);

  if (ws_size >= WS_NEED_BYTES) {
    k_expand <<<B_N / 32, 256, 0, stream>>>(diffc, V);
    k_padzero<<<(CH * NCOLP + 255) / 256, 256, 0, stream>>>(V);
    k_main<0><<<dim3(NT, NT, K_N), 256, 0, stream>>>(V, cw, offsp, lossA, ctr, out);
  } else {
    k_main<1><<<dim3(NT, NT, K_N), 256, 0, stream>>>(diffc, cw, offsp, lossA, ctr, out);
  }
}

// Round 5
// 106.408 us; speedup vs baseline: 1.5319x; 1.5319x over previous
//
#include <hip/hip_runtime.h>
#include <math.h>

#define B_N 2048
#define DIM 32
#define K_N 10
#define NP  528          // sorted pairs (i<=j)
#define NCOLP 640        // padded column count (5 tiles x 128)
#define CH 32            // samples per chunk
#define TILE 128
#define NT 5
#define NBLK (NT*NT*K_N)

// ---- ws layout (4-byte words) ----
#define WS_LOSS   0
#define WS_CTR    1
#define WS_CW     2
#define WS_CURSOR 12
#define WS_OFFS   22
#define WS_KB     32
#define WS_DIFFC  2080                 // 16B aligned; 2048*32 floats
#define WS_V      67616                // 16B aligned; 2048*640 floats
#define WS_NEED_BYTES ((size_t)(WS_V + (size_t)B_N * NCOLP) * 4)

__device__ __forceinline__ float c2f(float x) {
  float r = sqrtf(fabsf(x) + 0.25f) - 0.5f;
  return (x >= 0.f) ? r : -r;
}
__device__ __forceinline__ float c3f(float x) {
  float r = cbrtf(fabsf(x) + 0.19245008973f) - 0.57735026919f;
  return (x >= 0.f) ? r : -r;
}
__device__ __forceinline__ float c4f(float x) {
  float r = sqrtf(sqrtf(fabsf(x) + 0.15749013123f)) - 0.62996052494f;
  return (x >= 0.f) ? r : -r;
}
#define T4C1 (sqrtf(sqrtf(1.f + 0.15749013123f)) - 0.62996052494f)

// col -> (u,v) with d[32]=1 (ones), d[33]=0 (pad)
__device__ __forceinline__ void decode_col(int g, int& u, int& v) {
  if (g < NP) {
    int j = 0;
    while ((j + 1) * (j + 2) / 2 <= g) ++j;
    u = g - j * (j + 1) / 2; v = j;
  } else if (g < 560) { u = g - NP; v = 32; }
  else if (g == 560)  { u = 32; v = 32; }
  else                { u = 33; v = 33; }
}

// ---- kernel 1: argmax assignment + counts ----
__global__ void k_assign(const float* __restrict__ logits, int* __restrict__ cw,
                         int* __restrict__ kb) {
  int b = blockIdx.x * 256 + threadIdx.x;
  if (b >= B_N) return;
  const float* lg = logits + (size_t)b * K_N;
  float best = lg[0]; int bi = 0;
  #pragma unroll
  for (int k = 1; k < K_N; ++k) { float v = lg[k]; if (v > best) { best = v; bi = k; } }
  kb[b] = bi;
  atomicAdd(&cw[bi], 1);
}

// ---- kernel 2: exclusive scan over K=10 ----
__global__ void k_scan(const int* __restrict__ cw, int* __restrict__ offs) {
  if (threadIdx.x == 0) { int s = 0; for (int k = 0; k < K_N; ++k) { offs[k] = s; s += cw[k]; } }
}

// ---- kernel 3: compact scatter of diff vectors ----
__global__ void k_scatter(const float* __restrict__ emb, const float* __restrict__ cen,
                          const int* __restrict__ kb, const int* __restrict__ offs,
                          int* __restrict__ cursor, float* __restrict__ diffc) {
  int b = blockIdx.x * 256 + threadIdx.x;
  if (b >= B_N) return;
  int k = kb[b];
  int pos = offs[k] + atomicAdd(&cursor[k], 1);
  const float4* e4 = reinterpret_cast<const float4*>(emb + (size_t)b * DIM);
  const float4* c4p = reinterpret_cast<const float4*>(cen + (size_t)k * DIM);
  float4* o4 = reinterpret_cast<float4*>(diffc + (size_t)pos * DIM);
  #pragma unroll
  for (int q = 0; q < 8; ++q) {
    float4 e = e4[q], c = c4p[q];
    o4[q] = make_float4(e.x - c.x, e.y - c.y, e.z - c.z, e.w - c.w);
  }
}

// ---- kernel 4: expand diffc -> V[2048][640]; 8 rows/block, cols in registers ----
__global__ __launch_bounds__(256) void k_expand(const float* __restrict__ diffc,
                                                float* __restrict__ V) {
  __shared__ float sd[8][36];
  const int t = threadIdx.x;
  const int base = blockIdx.x * 8;
  if (t < 64) {
    int row = t >> 3, d4 = t & 7;
    float4 v = *reinterpret_cast<const float4*>(&diffc[(size_t)(base + row) * DIM + d4 * 4]);
    *reinterpret_cast<float4*>(&sd[row][d4 * 4]) = v;
    if (d4 == 0) { sd[row][32] = 1.f; sd[row][33] = 0.f; }
  }
  // decode my (up to 3) columns into registers
  int u0, v0, u1, v1, u2, v2;
  decode_col(t, u0, v0);
  decode_col(t + 256, u1, v1);
  decode_col(t + 512, u2, v2);
  __syncthreads();
  #pragma unroll
  for (int r = 0; r < 8; ++r) {
    float* vr = V + (size_t)(base + r) * NCOLP;
    vr[t]       = sd[r][u0] * sd[r][v0];
    vr[t + 256] = sd[r][u1] * sd[r][v1];
    if (t < 128) vr[t + 512] = sd[r][u2] * sd[r][v2];
  }
}

// ---- kernel 5: Gram + fused loss. MODE 0: V precomputed; MODE 1: products in-kernel ----
template<int MODE>
__global__ __launch_bounds__(256) void k_main(const float* __restrict__ src,
                                              const int* __restrict__ cw,
                                              const int* __restrict__ offs,
                                              float* __restrict__ lossAcc,
                                              int* __restrict__ ctr,
                                              float* __restrict__ out) {
  const int k  = blockIdx.z;
  const int Pt = blockIdx.y, Qt = blockIdx.x;
  const int nb = cw[k], boff = offs[k];
  const int t  = threadIdx.x;

  __shared__ __align__(16) float sPa[CH][64], sPb[CH][64];
  __shared__ __align__(16) float sQa[CH][64], sQb[CH][64];
  __shared__ __align__(16) float sd[MODE ? CH : 1][36];
  __shared__ unsigned char tIP[2][TILE], tIQ[2][TILE];
  __shared__ float sred[4];

  // decode column identity tables (also per-thread u,v for MODE 1 products)
  int myu, myv;
  {
    int side = t >> 7, c = t & 127;
    int g = (side ? Qt : Pt) * TILE + c;
    decode_col(g, myu, myv);
    if (side) { tIQ[0][c] = (unsigned char)myu; tIQ[1][c] = (unsigned char)myv; }
    else      { tIP[0][c] = (unsigned char)myu; tIP[1][c] = (unsigned char)myv; }
  }
  __syncthreads();

  float acc[8][8];
  #pragma unroll
  for (int a = 0; a < 8; ++a)
    #pragma unroll
    for (int c = 0; c < 8; ++c) acc[a][c] = 0.f;

  const int tp = t >> 4, tq = t & 15;

  for (int c0 = 0; c0 < nb; c0 += CH) {
    if (MODE == 0) {
      // stage BOTH panels [CH rows][128 cols] into split arrays, zero past nb.
      // float4 at cols 4*c4..4*c4+3 -> (c4&1 ? *b : *a)[row] + (c4>>1)*4
      #pragma unroll
      for (int pass = 0; pass < 4; ++pass) {      // P panel: 1024 float4
        int idx = t + pass * 256;
        int row = idx >> 5, c4 = idx & 31;
        float4 v = make_float4(0.f, 0.f, 0.f, 0.f);
        if (c0 + row < nb)
          v = *reinterpret_cast<const float4*>(
                &src[(size_t)(boff + c0 + row) * NCOLP + Pt * TILE + c4 * 4]);
        float* dst = ((c4 & 1) ? &sPb[row][0] : &sPa[row][0]) + (c4 >> 1) * 4;
        *reinterpret_cast<float4*>(dst) = v;
      }
      #pragma unroll
      for (int pass = 0; pass < 4; ++pass) {      // Q panel
        int idx = t + pass * 256;
        int row = idx >> 5, c4 = idx & 31;
        float4 v = make_float4(0.f, 0.f, 0.f, 0.f);
        if (c0 + row < nb)
          v = *reinterpret_cast<const float4*>(
                &src[(size_t)(boff + c0 + row) * NCOLP + Qt * TILE + c4 * 4]);
        float* dst = ((c4 & 1) ? &sQb[row][0] : &sQa[row][0]) + (c4 >> 1) * 4;
        *reinterpret_cast<float4*>(dst) = v;
      }
    } else {
      // stage raw d, then products in-LDS (round-2 path, validated)
      {
        int row = t >> 3, d4 = t & 7;
        float4 v = make_float4(0.f, 0.f, 0.f, 0.f);
        if (c0 + row < nb)
          v = *reinterpret_cast<const float4*>(&src[(size_t)(boff + c0 + row) * DIM + d4 * 4]);
        *reinterpret_cast<float4*>(&sd[row][d4 * 4]) = v;
        if (d4 == 0) { sd[row][32] = (c0 + row < nb) ? 1.f : 0.f; sd[row][33] = 0.f; }
      }
      __syncthreads();
      {
        int side = t >> 7, c = t & 127;
        float* dst = (side ? ((c & 4) ? &sQb[0][0] : &sQa[0][0])
                           : ((c & 4) ? &sPb[0][0] : &sPa[0][0]))
                     + ((c >> 3) * 4 + (c & 3));
        #pragma unroll
        for (int bb = 0; bb < CH; ++bb)
          dst[bb * 64] = sd[bb][myu] * sd[bb][myv];
      }
    }
    __syncthreads();

    #pragma unroll
    for (int bb = 0; bb < CH; ++bb) {
      float4 p0 = *reinterpret_cast<const float4*>(&sPa[bb][tp * 4]);
      float4 p1 = *reinterpret_cast<const float4*>(&sPb[bb][tp * 4]);
      float4 q0 = *reinterpret_cast<const float4*>(&sQa[bb][tq * 4]);
      float4 q1 = *reinterpret_cast<const float4*>(&sQb[bb][tq * 4]);
      float pa[8] = {p0.x, p0.y, p0.z, p0.w, p1.x, p1.y, p1.z, p1.w};
      float qa[8] = {q0.x, q0.y, q0.z, q0.w, q1.x, q1.y, q1.z, q1.w};
      #pragma unroll
      for (int a = 0; a < 8; ++a)
        #pragma unroll
        for (int c = 0; c < 8; ++c)
          acc[a][c] += pa[a] * qa[c];
    }
    __syncthreads();
  }

  // ---- fused epilogue (validated in round 2, absmax 0) ----
  const float inv_cnt = 1.f / ((float)nb + 1e-7f);
  float sum = 0.f;
  #pragma unroll
  for (int a = 0; a < 8; ++a) {
    int P = Pt * TILE + tp * 8 + a;
    int i = tIP[0][tp * 8 + a], j = tIP[1][tp * 8 + a];
    #pragma unroll
    for (int c = 0; c < 8; ++c) {
      int Q = Qt * TILE + tq * 8 + c;
      int l = tIQ[0][tq * 8 + c], m = tIQ[1][tq * 8 + c];
      float g = acc[a][c];
      if (P < NP) {
        if (Q < NP) {
          int s0 = min(i, l), a1 = max(i, l), a2 = min(j, m), s3 = max(j, m);
          int s1 = min(a1, a2), s2 = max(a1, a2);
          bool e01 = (s0 == s1), e12 = (s1 == s2), e23 = (s2 == s3);
          float wgt, tgt = 0.f;
          if (e01 && e12 && e23)                 wgt = 0.f;
          else if (e01 && e23)                   { wgt = 2.f / 9.f; tgt = T4C1; }
          else if ((e01 && e12) || (e12 && e23)) wgt = 0.25f;
          else if (e01 || e12 || e23)            wgt = 5.f / 24.f;
          else                                   wgt = 1.f / 6.f;
          float d = c4f(g) - tgt;
          sum += 0.125f * wgt * d * d;
        } else if (Q < 560) {
          int ll = Q - NP;
          if (ll >= j) { float d = c3f(g); sum += 0.25f * d * d; }
        } else if (Q == 560) {
          if (i < j) { float d = c2f(g * inv_cnt); sum += 0.5f * d * d; }
        }
      } else if (P < 560 && Q == 560) {
        float m1 = g * inv_cnt;
        sum += m1 * m1;
      }
    }
  }

  #pragma unroll
  for (int off = 32; off > 0; off >>= 1) sum += __shfl_down(sum, off, 64);
  if ((t & 63) == 0) sred[t >> 6] = sum;
  __syncthreads();
  if (t == 0) {
    float s = sred[0] + sred[1] + sred[2] + sred[3];
    atomicAdd(lossAcc, s * ((float)nb * (1.f / (float)B_N)));
    __threadfence();
    if (atomicAdd(ctr, 1) == NBLK - 1) out[0] = atomicAdd(lossAcc, 0.f);
  }
}

extern "C" void kernel_launch(void* const* d_in, const int* in_sizes, int n_in,
                              void* d_out, int out_size, void* d_ws, size_t ws_size,
                              hipStream_t stream) {
  const float* emb = (const float*)d_in[0];
  const float* cen = (const float*)d_in[1];
  const float* lg  = (const float*)d_in[2];
  float* out = (float*)d_out;

  int*   wsi    = (int*)d_ws;
  float* wsf    = (float*)d_ws;
  float* lossA  = wsf + WS_LOSS;
  int*   ctr    = wsi + WS_CTR;
  int*   cw     = wsi + WS_CW;
  int*   cursor = wsi + WS_CURSOR;
  int*   offsp  = wsi + WS_OFFS;
  int*   kb     = wsi + WS_KB;
  float* diffc  = wsf + WS_DIFFC;
  float* V      = wsf + WS_V;

  (void)hipMemsetAsync(d_ws, 0, 64 * 4, stream);
  k_assign <<<B_N / 256, 256, 0, stream>>>(lg, cw, kb);
  k_scan   <<<1, 64, 0, stream>>>(cw, offsp);
  k_scatter<<<B_N / 256, 256, 0, stream>>>(emb, cen, kb, offsp, cursor, diffc);

  if (ws_size >= WS_NEED_BYTES) {
    k_expand<<<B_N / 8, 256, 0, stream>>>(diffc, V);
    k_main<0><<<dim3(NT, NT, K_N), 256, 0, stream>>>(V, cw, offsp, lossA, ctr, out);
  } else {
    k_main<1><<<dim3(NT, NT, K_N), 256, 0, stream>>>(diffc, cw, offsp, lossA, ctr, out);
  }
}

// Round 6
// 66.104 us; speedup vs baseline: 2.4659x; 1.6097x over previous
//
#include <hip/hip_runtime.h>
#include <math.h>

#define B_N 2048
#define DIM 32
#define K_N 10
#define NP  528          // sorted pairs (i<=j)
#define NCOLP 640        // padded column count (5 tiles x 128)
#define TILE 128
#define NT 5
#define NBLK (NT*NT*K_N)
#define NR 2368          // padded sample rows: 2048 + 10*32

typedef __attribute__((ext_vector_type(8))) short bf16x8;   // 8 bf16 = 4 VGPRs
typedef __attribute__((ext_vector_type(4))) float f32x4;    // mfma 16x16 accum

// ---- ws layout (4-byte words) ----
#define WS_CW     0               // cw[10]
#define WS_CURSOR 16              // cursor[10]
#define WS_OFFP   32              // offp[11] (padded exclusive scan)
#define WS_LOSS   48
#define WS_CTR    49
#define WS_KB     64              // kb[2048]
#define WS_DIFFC  2112            // 2368*32 floats = 75776 words (16B aligned)
#define WS_VT     (2112 + 75776)  // 77888 words -> byte 311552 (16B aligned); ushort[640*2368]

__device__ __forceinline__ float c2f(float x) {
  float r = sqrtf(fabsf(x) + 0.25f) - 0.5f;
  return (x >= 0.f) ? r : -r;
}
__device__ __forceinline__ float c3f(float x) {
  float r = cbrtf(fabsf(x) + 0.19245008973f) - 0.57735026919f;
  return (x >= 0.f) ? r : -r;
}
__device__ __forceinline__ float c4f(float x) {
  float r = sqrtf(sqrtf(fabsf(x) + 0.15749013123f)) - 0.62996052494f;
  return (x >= 0.f) ? r : -r;
}
#define T4C1 (sqrtf(sqrtf(1.f + 0.15749013123f)) - 0.62996052494f)

// col -> (u,v) with d[32]=1 (ones), d[33]=0 (pad)
__device__ __forceinline__ void decode_col(int g, int& u, int& v) {
  if (g < NP) {
    int j = (int)((sqrtf(8.f * (float)g + 1.f) - 1.f) * 0.5f);
    while (j * (j + 1) / 2 > g) --j;
    while ((j + 1) * (j + 2) / 2 <= g) ++j;
    u = g - j * (j + 1) / 2; v = j;
  } else if (g < 560) { u = g - NP; v = 32; }
  else if (g == 560)  { u = 32; v = 32; }
  else                { u = 33; v = 33; }
}

// fp32 -> bf16 bits, round-to-nearest-even
__device__ __forceinline__ unsigned short f2bf(float f) {
  unsigned u = __builtin_bit_cast(unsigned, f);
  return (unsigned short)((u + 0x7FFFu + ((u >> 16) & 1u)) >> 16);
}

// ---- kernel 1: argmax assignment + counts ----
__global__ void k_assign(const float* __restrict__ logits, int* __restrict__ cw,
                         int* __restrict__ kb) {
  int b = blockIdx.x * 256 + threadIdx.x;
  if (b >= B_N) return;
  const float* lg = logits + (size_t)b * K_N;
  float best = lg[0]; int bi = 0;
  #pragma unroll
  for (int k = 1; k < K_N; ++k) { float v = lg[k]; if (v > best) { best = v; bi = k; } }
  kb[b] = bi;
  atomicAdd(&cw[bi], 1);
}

// ---- kernel 2: padded exclusive scan over K=10 ----
__global__ void k_scan(const int* __restrict__ cw, int* __restrict__ offp,
                       float* __restrict__ lossAcc, int* __restrict__ ctr) {
  if (threadIdx.x == 0) {
    int s = 0;
    for (int k = 0; k < K_N; ++k) { offp[k] = s; s += (cw[k] + 31) & ~31; }
    offp[K_N] = s;
    *lossAcc = 0.f; *ctr = 0;
  }
}

// ---- kernel 3: compact scatter into padded layout + zero pad/tail rows ----
__global__ void k_scatter(const float* __restrict__ emb, const float* __restrict__ cen,
                          const int* __restrict__ kb, const int* __restrict__ cw,
                          const int* __restrict__ offp, int* __restrict__ cursor,
                          float* __restrict__ diffc) {
  int t = blockIdx.x * 256 + threadIdx.x;
  if (t < B_N) {
    int k = kb[t];
    int pos = offp[k] + atomicAdd(&cursor[k], 1);
    const float4* e4 = reinterpret_cast<const float4*>(emb + (size_t)t * DIM);
    const float4* c4p = reinterpret_cast<const float4*>(cen + (size_t)k * DIM);
    float4* o4 = reinterpret_cast<float4*>(diffc + (size_t)pos * DIM);
    #pragma unroll
    for (int q = 0; q < 8; ++q) {
      float4 e = e4[q], c = c4p[q];
      o4[q] = make_float4(e.x - c.x, e.y - c.y, e.z - c.z, e.w - c.w);
    }
  } else if (t < NR) {
    // zero the NR - B_N = 320 pad/tail rows
    int p = t - B_N;
    int cp = 0, row = -1;
    #pragma unroll
    for (int kk = 0; kk < K_N; ++kk) {
      int nb = cw[kk];
      int pad = ((nb + 31) & ~31) - nb;
      if (row < 0 && p < cp + pad) row = offp[kk] + nb + (p - cp);
      cp += pad;
    }
    if (row < 0) row = offp[K_N] + (p - cp);
    float4* o4 = reinterpret_cast<float4*>(diffc + (size_t)row * DIM);
    #pragma unroll
    for (int q = 0; q < 8; ++q) o4[q] = make_float4(0.f, 0.f, 0.f, 0.f);
  }
}

// ---- kernel 4: expand diffc -> Vt[640 cols][NR samples] in bf16 (transposed) ----
__global__ __launch_bounds__(256) void k_expand(const float* __restrict__ diffc,
                                                unsigned short* __restrict__ Vt) {
  __shared__ float sd[64][36];
  const int t = threadIdx.x;
  const int base = blockIdx.x * 64;
  {
    int row = t >> 2, part = t & 3;
    const float4* src = reinterpret_cast<const float4*>(diffc + (size_t)(base + row) * DIM);
    float4 v0 = src[part * 2], v1 = src[part * 2 + 1];
    *reinterpret_cast<float4*>(&sd[row][part * 8]) = v0;
    *reinterpret_cast<float4*>(&sd[row][part * 8 + 4]) = v1;
    if (part == 0) { sd[row][32] = 1.f; sd[row][33] = 0.f; }
  }
  __syncthreads();
  for (int c = t; c < NCOLP; c += 256) {
    int u, v; decode_col(c, u, v);
    unsigned short* dst = Vt + (size_t)c * NR + base;
    #pragma unroll
    for (int r8 = 0; r8 < 8; ++r8) {
      bf16x8 pack;
      #pragma unroll
      for (int e = 0; e < 8; ++e)
        pack[e] = (short)f2bf(sd[r8 * 8 + e][u] * sd[r8 * 8 + e][v]);
      *reinterpret_cast<bf16x8*>(dst + r8 * 8) = pack;
    }
  }
}

// ---- kernel 5: MFMA Gram + fused loss ----
__global__ __launch_bounds__(256) void k_main(const unsigned short* __restrict__ Vt,
                                              const int* __restrict__ cw,
                                              const int* __restrict__ offp,
                                              float* __restrict__ lossAcc,
                                              int* __restrict__ ctr,
                                              float* __restrict__ out) {
  const int k  = blockIdx.z;
  const int Pt = blockIdx.y, Qt = blockIdx.x;
  const int nb = cw[k];
  const int base = offp[k];
  const int nbp = (nb + 31) & ~31;
  const int t = threadIdx.x;
  const int w = t >> 6, l = t & 63;
  const int wr = w >> 1, wc = w & 1;
  const int lr = l & 15, kg = l >> 4;

  __shared__ unsigned char tI0[NCOLP], tI1[NCOLP];
  __shared__ float sred[4];
  for (int c = t; c < NCOLP; c += 256) {
    int u, v; decode_col(c, u, v);
    tI0[c] = (unsigned char)u; tI1[c] = (unsigned char)v;
  }

  const int pb = Pt * TILE + wr * 64;   // wave's P quadrant base
  const int qb = Qt * TILE + wc * 64;   // wave's Q quadrant base

  f32x4 acc[4][4];
  {
    f32x4 z = {0.f, 0.f, 0.f, 0.f};
    #pragma unroll
    for (int a = 0; a < 4; ++a)
      #pragma unroll
      for (int c = 0; c < 4; ++c) acc[a][c] = z;
  }

  if (nbp > 0) {
    // frag: lane holds col = pb/qb + f*16 + lr, samples k0 + kg*8 .. +7
    const unsigned short* Ap = Vt + (size_t)(pb + lr) * NR + base + kg * 8;
    const unsigned short* Bp = Vt + (size_t)(qb + lr) * NR + base + kg * 8;
    bf16x8 a[4], b[4];
    #pragma unroll
    for (int f = 0; f < 4; ++f) {
      a[f] = *reinterpret_cast<const bf16x8*>(Ap + (size_t)(f * 16) * NR);
      b[f] = *reinterpret_cast<const bf16x8*>(Bp + (size_t)(f * 16) * NR);
    }
    for (int k0 = 32; k0 <= nbp; k0 += 32) {
      bf16x8 an[4], bn[4];
      const bool more = (k0 < nbp);
      if (more) {                       // prefetch next K-chunk during MFMA burst
        #pragma unroll
        for (int f = 0; f < 4; ++f) {
          an[f] = *reinterpret_cast<const bf16x8*>(Ap + (size_t)(f * 16) * NR + k0);
          bn[f] = *reinterpret_cast<const bf16x8*>(Bp + (size_t)(f * 16) * NR + k0);
        }
      }
      #pragma unroll
      for (int fa = 0; fa < 4; ++fa)
        #pragma unroll
        for (int fc = 0; fc < 4; ++fc)
          acc[fa][fc] = __builtin_amdgcn_mfma_f32_16x16x32_bf16(a[fa], b[fc], acc[fa][fc], 0, 0, 0);
      if (more) {
        #pragma unroll
        for (int f = 0; f < 4; ++f) { a[f] = an[f]; b[f] = bn[f]; }
      }
    }
  }
  __syncthreads();   // tI tables ready for epilogue

  // ---- fused epilogue (algebra validated absmax=0 in rounds 2/5) ----
  // C/D layout (m89-verified): Q(col) = lane&15, P(row) = (lane>>4)*4 + reg
  const float inv_cnt = 1.f / ((float)nb + 1e-7f);
  float sum = 0.f;
  #pragma unroll
  for (int fa = 0; fa < 4; ++fa) {
    #pragma unroll
    for (int r = 0; r < 4; ++r) {
      const int P = pb + fa * 16 + kg * 4 + r;
      const int i = tI0[P], j = tI1[P];
      #pragma unroll
      for (int fc = 0; fc < 4; ++fc) {
        const int Q = qb + fc * 16 + lr;
        const int li = tI0[Q], mi = tI1[Q];
        const float g = acc[fa][fc][r];
        if (P < NP) {
          if (Q < NP) {
            int s0 = min(i, li), x1 = max(i, li), x2 = min(j, mi), s3 = max(j, mi);
            int s1 = min(x1, x2), s2 = max(x1, x2);
            bool e01 = (s0 == s1), e12 = (s1 == s2), e23 = (s2 == s3);
            float wgt, tgt = 0.f;
            if (e01 && e12 && e23)                 wgt = 0.f;
            else if (e01 && e23)                   { wgt = 2.f / 9.f; tgt = T4C1; }
            else if ((e01 && e12) || (e12 && e23)) wgt = 0.25f;
            else if (e01 || e12 || e23)            wgt = 5.f / 24.f;
            else                                   wgt = 1.f / 6.f;
            float d = c4f(g) - tgt;
            sum += 0.125f * wgt * d * d;
          } else if (Q < 560) {
            if (Q - NP >= j) { float d = c3f(g); sum += 0.25f * d * d; }
          } else if (Q == 560) {
            if (i < j) { float d = c2f(g * inv_cnt); sum += 0.5f * d * d; }
          }
        } else if (P < 560 && Q == 560) {
          float m1 = g * inv_cnt;
          sum += m1 * m1;
        }
      }
    }
  }

  #pragma unroll
  for (int off = 32; off > 0; off >>= 1) sum += __shfl_down(sum, off, 64);
  if ((t & 63) == 0) sred[t >> 6] = sum;
  __syncthreads();
  if (t == 0) {
    float s = sred[0] + sred[1] + sred[2] + sred[3];
    atomicAdd(lossAcc, s * ((float)nb * (1.f / (float)B_N)));
    __threadfence();
    if (atomicAdd(ctr, 1) == NBLK - 1) out[0] = atomicAdd(lossAcc, 0.f);
  }
}

extern "C" void kernel_launch(void* const* d_in, const int* in_sizes, int n_in,
                              void* d_out, int out_size, void* d_ws, size_t ws_size,
                              hipStream_t stream) {
  const float* emb = (const float*)d_in[0];
  const float* cen = (const float*)d_in[1];
  const float* lg  = (const float*)d_in[2];
  float* out = (float*)d_out;

  int*   wsi    = (int*)d_ws;
  float* wsf    = (float*)d_ws;
  int*   cw     = wsi + WS_CW;
  int*   cursor = wsi + WS_CURSOR;
  int*   offp   = wsi + WS_OFFP;
  float* lossA  = wsf + WS_LOSS;
  int*   ctr    = wsi + WS_CTR;
  int*   kb     = wsi + WS_KB;
  float* diffc  = wsf + WS_DIFFC;
  unsigned short* Vt = (unsigned short*)(wsf + WS_VT);

  (void)hipMemsetAsync(d_ws, 0, 64 * 4, stream);              // cw, cursor, offp, loss, ctr
  k_assign <<<B_N / 256, 256, 0, stream>>>(lg, cw, kb);
  k_scan   <<<1, 64, 0, stream>>>(cw, offp, lossA, ctr);
  k_scatter<<<(NR + 255) / 256, 256, 0, stream>>>(emb, cen, kb, cw, offp, cursor, diffc);
  k_expand <<<NR / 64, 256, 0, stream>>>(diffc, Vt);
  k_main   <<<dim3(NT, NT, K_N), 256, 0, stream>>>(Vt, cw, offp, lossA, ctr, out);
}